// Round 6
// baseline (765.896 us; speedup 1.0000x reference)
//
#include <hip/hip_runtime.h>
#include <hip/hip_fp16.h>
#include <math.h>

#define B_   4096
#define D_   1792
#define NC_  3000
#define NM_  7000
#define NF_  13000
#define NCP  3072                /* 12 x 256 */
#define NMP  7168                /* 28 x 256 */
#define NFP  13312               /* 52 x 256 */
#define NTOT (NCP + NMP + NFP)   /* 23552 = 92 x 256 */
#define OFFC 0
#define OFFM NCP                 /* 3072 */
#define OFFF (NCP + NMP)         /* 10240 */
#define WROWS 8192               /* wTbuf rows: 32 col-tiles per GEMM launch */
#define DEG2RAD 0.017453292519943295f

typedef _Float16 half8  __attribute__((ext_vector_type(8)));
typedef _Float16 half4v __attribute__((ext_vector_type(4)));
typedef float    f32x4  __attribute__((ext_vector_type(4)));

__device__ __forceinline__ void async16(const void* g, void* l) {
  __builtin_amdgcn_global_load_lds(
      (const __attribute__((address_space(1))) void*)g,
      (__attribute__((address_space(3))) void*)l, 16, 0, 0);
}

// ---------------- prep: bias concat, trig tables, accumulator zero ----------------
__global__ void prep_kernel(const float* __restrict__ labels,
                            const float* __restrict__ cp, const float* __restrict__ mp,
                            const float* __restrict__ fp,
                            const float* __restrict__ cb, const float* __restrict__ mb,
                            const float* __restrict__ fb,
                            float* __restrict__ bias, float4* __restrict__ ptrig,
                            float4* __restrict__ ltrig, float* __restrict__ accum) {
  int i = blockIdx.x * 256 + threadIdx.x;
  if (i < NTOT) {
    float v = 0.f;
    if (i < OFFM)      { if (i < NC_) v = cb[i]; }
    else if (i < OFFF) { int j = i - OFFM; if (j < NM_) v = mb[j]; }
    else               { int j = i - OFFF; if (j < NF_) v = fb[j]; }
    bias[i] = v;
  }
  if (i < NC_ + NM_ + NF_) {
    const float* src; int j = i;
    if (i < NC_)            { src = cp; }
    else if (i < NC_ + NM_) { src = mp; j = i - NC_; }
    else                    { src = fp; j = i - NC_ - NM_; }
    float la = src[2 * j] * DEG2RAD, lo = src[2 * j + 1] * DEG2RAD;
    float sla, cla, slo, clo;
    sincosf(la, &sla, &cla); sincosf(lo, &slo, &clo);
    ptrig[i] = make_float4(sla, cla, slo, clo);
  }
  if (i < B_) {
    float la = labels[2 * i] * DEG2RAD, lo = labels[2 * i + 1] * DEG2RAD;
    float sla, cla, slo, clo;
    sincosf(la, &sla, &cla); sincosf(lo, &slo, &clo);
    ltrig[i] = make_float4(sla, cla, slo, clo);
  }
  if (i < 64) accum[i] = 0.f;
}

// ---------------- features fp32 -> fp16 ----------------
__global__ void cvt_feat(const float4* __restrict__ in, half4v* __restrict__ out) {
  int i = blockIdx.x * 256 + threadIdx.x;  // exactly B_*D_/4 threads
  float4 v = in[i];
  half4v h;
  h[0] = (_Float16)v.x; h[1] = (_Float16)v.y; h[2] = (_Float16)v.z; h[3] = (_Float16)v.w;
  out[i] = h;
}

// ---- weight chunk [K][Nfull] fp32 -> [rows][K] fp16 (transpose, pad rows -> 0) ----
__global__ void transpose_w(const float* __restrict__ w, _Float16* __restrict__ wt,
                            int Nfull, int c0, int ntrue_chunk) {
  __shared__ float tile[32][33];
  int n0 = blockIdx.x * 32, k0 = blockIdx.y * 32;
  int tx = threadIdx.x, ty = threadIdx.y;  // 32 x 8
#pragma unroll
  for (int i = 0; i < 4; ++i) {
    int kk = ty + i * 8;
    int n = n0 + tx;
    float v = (n < ntrue_chunk) ? w[(size_t)(k0 + kk) * Nfull + c0 + n] : 0.f;
    tile[kk][tx] = v;
  }
  __syncthreads();
#pragma unroll
  for (int i = 0; i < 4; ++i) {
    int nn = ty + i * 8;
    wt[(size_t)(n0 + nn) * D_ + k0 + tx] = (_Float16)tile[tx][nn];
  }
}

// ---------------- haversine argmin labels (monotone: compare 'a' only) ----------------
__global__ void argmin_kernel(const float4* __restrict__ ptrig, const float4* __restrict__ ltrig,
                              int* __restrict__ lidx) {
  __shared__ float rv[256];
  __shared__ int ri[256];
  int b = blockIdx.x, tid = threadIdx.x;
  float4 lt = ltrig[b];
  const int base[3] = {0, NC_, NC_ + NM_};
  const int cnt[3]  = {NC_, NM_, NF_};
#pragma unroll
  for (int h = 0; h < 3; ++h) {
    float best = 1e30f; int bi = 0;
    for (int i = tid; i < cnt[h]; i += 256) {
      float4 pt = ptrig[base[h] + i];
      float cdla = lt.y * pt.y + lt.x * pt.x;
      float cdlo = lt.w * pt.w + lt.z * pt.z;
      float a = 0.5f * (1.f - cdla) + (lt.y * pt.y) * 0.5f * (1.f - cdlo);
      if (a < best) { best = a; bi = i; }
    }
    rv[tid] = best; ri[tid] = bi;
    __syncthreads();
    for (int o = 128; o; o >>= 1) {
      if (tid < o) {
        if (rv[tid + o] < rv[tid] || (rv[tid + o] == rv[tid] && ri[tid + o] < ri[tid])) {
          rv[tid] = rv[tid + o]; ri[tid] = ri[tid + o];
        }
      }
      __syncthreads();
    }
    if (tid == 0) lidx[h * B_ + b] = ri[0];
    __syncthreads();
  }
}

// ==== fp16 MFMA GEMM: 256x256 tile, 8 waves, 56 K-phases of 32, reg-pipelined ====
// LDS (128 KiB, halfs): A regions r=0..3 at r*8192 (each [256r][4slot][8], K=32);
// B regions at 32768 + r*8192. Swizzle: slot s holds kb = s ^ ((row>>1)&3).
// Phase P: MFMAs consume frags loaded during P-1; af[tm] reloaded from region
// (P+1)%4 after its last use; bf after the cluster. stage(P) -> data(P+4).
// Boundary: s_waitcnt vmcnt(8) + lgkmcnt(0) + sched_barrier + s_barrier.
// R5 diagnosis: LLVM clustered all 12 ds_reads AFTER the 32 MFMAs -> phase =
// MFMA + LDS in SUM (2411 cyc measured = 1242 + 1152). Fix: sched_group_barrier
// pins 8 x {4 MFMA, 1 DS_READ} + 4 DS_READ so the LDS pipe drains UNDER the
// MFMA window (CK v3 pattern; masks: MFMA=0x8, DS_READ=0x100).
#define SGB_INTERLEAVE { \
    _Pragma("unroll") for (int g = 0; g < 8; ++g) { \
      __builtin_amdgcn_sched_group_barrier(0x8, 4, 0); \
      __builtin_amdgcn_sched_group_barrier(0x100, 1, 0); \
    } \
    __builtin_amdgcn_sched_group_barrier(0x100, 4, 0); }

__global__ __launch_bounds__(512, 2) void gemm_f16(const _Float16* __restrict__ A,
                                                   const _Float16* __restrict__ Bt,
                                                   const float* __restrict__ bias,
                                                   _Float16* __restrict__ C, int coff) {
  __shared__ _Float16 lds[65536];   // 128 KiB
  const int tid = threadIdx.x;
  const int lane = tid & 63, w = tid >> 6;      // 8 waves
  const int wm = w & 1, wn = w >> 1;            // 2 (M) x 4 (N)
  const int q = lane >> 4, l15 = lane & 15;
  // bijective XCD swizzle (gridDim.x is always a multiple of 8)
  const int q8 = gridDim.x >> 3;
  const int bxr = blockIdx.x;
  const int bx = (bxr & 7) * q8 + (bxr >> 3);
  const int mt = bx & 15, nt = bx >> 4;         // grid = 16 x tiles
  const int m0 = mt * 256;
  const int nl0 = nt * 256;                     // wTbuf-local col base
  const int gn0 = coff + nl0;                   // global col base (bias / C)

  f32x4 acc[8][4];
#pragma unroll
  for (int a = 0; a < 8; ++a)
#pragma unroll
    for (int b2 = 0; b2 < 4; ++b2) acc[a][b2] = (f32x4){0.f, 0.f, 0.f, 0.f};

  const int amB = (wm * 128 + l15) * 32;
  const int bnB = (wn * 64 + l15) * 32;
  const int xsl = ((q ^ ((l15 >> 1) & 3)) << 3);
  const int kbl = (lane & 3) ^ ((lane >> 3) & 3);
  const int rr = lane >> 2;

  auto stageP = [&](int r, int P) {
    const int kk = P * 32 + kbl * 8;
#pragma unroll
    for (int j = 0; j < 2; ++j) {
      int seg = w * 2 + j;
      async16(A  + (size_t)(m0  + seg * 16 + rr) * D_ + kk,
              (void*)(lds + r * 8192 + seg * 512));
      async16(Bt + (size_t)(nl0 + seg * 16 + rr) * D_ + kk,
              (void*)(lds + 32768 + r * 8192 + seg * 512));
    }
  };

  half8 af[8], bf[4];

#define PHASE(RS, RN, WAITSTR, DOSTAGE, PST) { \
    if (DOSTAGE) stageP(RS, PST); \
    __builtin_amdgcn_s_setprio(1); \
    _Pragma("unroll") for (int tm = 0; tm < 8; ++tm) { \
      _Pragma("unroll") for (int tn = 0; tn < 4; ++tn) \
        acc[tm][tn] = __builtin_amdgcn_mfma_f32_16x16x32_f16(af[tm], bf[tn], acc[tm][tn], 0, 0, 0); \
      af[tm] = *(const half8*)(lds + (RN) * 8192 + amB + tm * 512 + xsl); \
    } \
    __builtin_amdgcn_s_setprio(0); \
    _Pragma("unroll") for (int tn = 0; tn < 4; ++tn) \
      bf[tn] = *(const half8*)(lds + 32768 + (RN) * 8192 + bnB + tn * 512 + xsl); \
    SGB_INTERLEAVE; \
    asm volatile(WAITSTR ::: "memory"); \
    __builtin_amdgcn_sched_barrier(0); \
    __builtin_amdgcn_s_barrier(); }

  // prologue: stage data(0..3); data(0),(1) complete; prefetch frags(data 0)
  stageP(0, 0); stageP(1, 1); stageP(2, 2); stageP(3, 3);
  asm volatile("s_waitcnt vmcnt(8)" ::: "memory");
  __builtin_amdgcn_sched_barrier(0);
  __builtin_amdgcn_s_barrier();
#pragma unroll
  for (int tm = 0; tm < 8; ++tm)
    af[tm] = *(const half8*)(lds + amB + tm * 512 + xsl);
#pragma unroll
  for (int tn = 0; tn < 4; ++tn)
    bf[tn] = *(const half8*)(lds + 32768 + bnB + tn * 512 + xsl);
  asm volatile("s_waitcnt lgkmcnt(0)" ::: "memory");
  __builtin_amdgcn_sched_barrier(0);
  __builtin_amdgcn_s_barrier();

  // main: phases 0..51 (13 iters x 4), stage P+4, vmcnt(8) boundaries
#pragma unroll 1
  for (int i = 0; i < 13; ++i) {
    const int P0 = 4 * i;
    PHASE(0, 1, "s_waitcnt vmcnt(8) lgkmcnt(0)", true, P0 + 4);
    PHASE(1, 2, "s_waitcnt vmcnt(8) lgkmcnt(0)", true, P0 + 5);
    PHASE(2, 3, "s_waitcnt vmcnt(8) lgkmcnt(0)", true, P0 + 6);
    PHASE(3, 0, "s_waitcnt vmcnt(8) lgkmcnt(0)", true, P0 + 7);
  }
  // epilogue: phases 52..55, no staging
  PHASE(0, 1, "s_waitcnt vmcnt(4) lgkmcnt(0)", false, 0);
  PHASE(0, 2, "s_waitcnt vmcnt(0) lgkmcnt(0)", false, 0);
  // phase 54: reload region 3 (data 55); compiler's dep-tracking orders the
  // ds_read -> MFMA wait for phase 55 (no cross-wave hazard remains)
  {
    __builtin_amdgcn_s_setprio(1);
#pragma unroll
    for (int tm = 0; tm < 8; ++tm) {
#pragma unroll
      for (int tn = 0; tn < 4; ++tn)
        acc[tm][tn] = __builtin_amdgcn_mfma_f32_16x16x32_f16(af[tm], bf[tn], acc[tm][tn], 0, 0, 0);
      af[tm] = *(const half8*)(lds + 3 * 8192 + amB + tm * 512 + xsl);
    }
    __builtin_amdgcn_s_setprio(0);
#pragma unroll
    for (int tn = 0; tn < 4; ++tn)
      bf[tn] = *(const half8*)(lds + 32768 + 3 * 8192 + bnB + tn * 512 + xsl);
    SGB_INTERLEAVE;
  }
  // phase 55: MFMA only
  {
    __builtin_amdgcn_s_setprio(1);
#pragma unroll
    for (int tm = 0; tm < 8; ++tm)
#pragma unroll
      for (int tn = 0; tn < 4; ++tn)
        acc[tm][tn] = __builtin_amdgcn_mfma_f32_16x16x32_f16(af[tm], bf[tn], acc[tm][tn], 0, 0, 0);
    __builtin_amdgcn_s_setprio(0);
  }
#undef PHASE

  // epilogue: bias add + fp16 store
  float bn[4];
#pragma unroll
  for (int tn = 0; tn < 4; ++tn) bn[tn] = bias[gn0 + wn * 64 + tn * 16 + l15];
#pragma unroll
  for (int tm = 0; tm < 8; ++tm) {
    int gm = m0 + wm * 128 + tm * 16 + q * 4;
#pragma unroll
    for (int tn = 0; tn < 4; ++tn) {
      int gn = gn0 + wn * 64 + tn * 16 + l15;
      _Float16* dst = C + (size_t)gm * NTOT + gn;
#pragma unroll
      for (int r = 0; r < 4; ++r) dst[(size_t)r * NTOT] = (_Float16)(acc[tm][tn][r] + bn[tn]);
    }
  }
}

// ---------------- block-wide LSE combine; returns broadcast result ----------------
__device__ __forceinline__ float block_lse(float m, float s, float* ms, float* ss, int tid) {
  ms[tid] = m; ss[tid] = s;
  __syncthreads();
  for (int o = 128; o; o >>= 1) {
    if (tid < o) {
      float m2 = ms[tid + o], s2 = ss[tid + o];
      if (m2 > ms[tid]) { ss[tid] = s2 + ss[tid] * __expf(ms[tid] - m2); ms[tid] = m2; }
      else ss[tid] += s2 * __expf(m2 - ms[tid]);
    }
    __syncthreads();
  }
  float r = ms[0] + logf(ss[0]);
  __syncthreads();   // protect ms/ss reuse by caller
  return r;
}

// ------- fused: per-row LSE x3 + NLL + hierarchical argmax + accuracy -------
__global__ __launch_bounds__(256) void final_kernel(const _Float16* __restrict__ logits,
                                                    const int* __restrict__ mpar,
                                                    const int* __restrict__ fpar,
                                                    const float4* __restrict__ ptrig,
                                                    const float4* __restrict__ ltrig,
                                                    const int* __restrict__ lidx,
                                                    float* __restrict__ nll_buf,
                                                    float* __restrict__ accum) {
  __shared__ float co[NC_];    // 12000 B
  __shared__ float par[NM_];   // 28000 B
  __shared__ float ms[256], ss[256];
  __shared__ int ri[256];
  int b = blockIdx.x, tid = threadIdx.x;
  const _Float16* row = logits + (size_t)b * NTOT;

  // ---- coarse: online LSE + stash fp32 copy to LDS ----
  float m = -1e30f, s = 0.f;
  {
    const half8* rc = (const half8*)(row + OFFC);
    for (int i = tid; i < NC_ / 8; i += 256) {
      half8 v = rc[i];
      float x[8];
#pragma unroll
      for (int j = 0; j < 8; ++j) x[j] = (float)v[j];
      float vm = fmaxf(fmaxf(fmaxf(x[0], x[1]), fmaxf(x[2], x[3])),
                       fmaxf(fmaxf(x[4], x[5]), fmaxf(x[6], x[7])));
      if (vm > m) { s *= __expf(m - vm); m = vm; }
#pragma unroll
      for (int j = 0; j < 8; ++j) s += __expf(x[j] - m);
      f32x4 lo = {x[0], x[1], x[2], x[3]}, hi = {x[4], x[5], x[6], x[7]};
      *(f32x4*)(co + i * 8)     = lo;
      *(f32x4*)(co + i * 8 + 4) = hi;
    }
  }
  float lseC = block_lse(m, s, ms, ss, tid);   // also fences co[] for readers

  // ---- middle: online LSE over raw logits; par = logit + co[mpar] ----
  m = -1e30f; s = 0.f;
  {
    const half8* rm = (const half8*)(row + OFFM);
    const int4* mp4 = (const int4*)mpar;
    for (int i = tid; i < NM_ / 8; i += 256) {
      half8 v = rm[i];
      int4 p0 = mp4[2 * i], p1 = mp4[2 * i + 1];
      float x[8];
#pragma unroll
      for (int j = 0; j < 8; ++j) x[j] = (float)v[j];
      float vm = fmaxf(fmaxf(fmaxf(x[0], x[1]), fmaxf(x[2], x[3])),
                       fmaxf(fmaxf(x[4], x[5]), fmaxf(x[6], x[7])));
      if (vm > m) { s *= __expf(m - vm); m = vm; }
#pragma unroll
      for (int j = 0; j < 8; ++j) s += __expf(x[j] - m);
      int pj[8] = {p0.x, p0.y, p0.z, p0.w, p1.x, p1.y, p1.z, p1.w};
      f32x4 lo = {x[0] + co[pj[0]], x[1] + co[pj[1]], x[2] + co[pj[2]], x[3] + co[pj[3]]};
      f32x4 hi = {x[4] + co[pj[4]], x[5] + co[pj[5]], x[6] + co[pj[6]], x[7] + co[pj[7]]};
      *(f32x4*)(par + i * 8)     = lo;
      *(f32x4*)(par + i * 8 + 4) = hi;
    }
  }
  float lseM = block_lse(m, s, ms, ss, tid);   // also fences par[] for readers

  // ---- fine: online LSE over raw logits; argmax of logit + par[fpar] ----
  m = -1e30f; s = 0.f;
  float best = -1e30f; int bi = 0;
  {
    const half8* rf = (const half8*)(row + OFFF);
    const int4* fp4 = (const int4*)fpar;
    for (int i = tid; i < NF_ / 8; i += 256) {
      half8 v = rf[i];
      int4 p0 = fp4[2 * i], p1 = fp4[2 * i + 1];
      float x[8];
#pragma unroll
      for (int j = 0; j < 8; ++j) x[j] = (float)v[j];
      float vm = fmaxf(fmaxf(fmaxf(x[0], x[1]), fmaxf(x[2], x[3])),
                       fmaxf(fmaxf(x[4], x[5]), fmaxf(x[6], x[7])));
      if (vm > m) { s *= __expf(m - vm); m = vm; }
#pragma unroll
      for (int j = 0; j < 8; ++j) s += __expf(x[j] - m);
      int pj[8] = {p0.x, p0.y, p0.z, p0.w, p1.x, p1.y, p1.z, p1.w};
#pragma unroll
      for (int j = 0; j < 8; ++j) {
        float vv = x[j] + par[pj[j]];
        if (vv > best) { best = vv; bi = i * 8 + j; }
      }
    }
  }
  float lseF = block_lse(m, s, ms, ss, tid);

  // ---- block argmax reduce (reuse ms as value buffer) ----
  ms[tid] = best; ri[tid] = bi;
  __syncthreads();
  for (int o = 128; o; o >>= 1) {
    if (tid < o) {
      if (ms[tid + o] > ms[tid] || (ms[tid + o] == ms[tid] && ri[tid + o] < ri[tid])) {
        ms[tid] = ms[tid + o]; ri[tid] = ri[tid + o];
      }
    }
    __syncthreads();
  }

  if (tid == 0) {
    int ic = lidx[b], im = lidx[B_ + b], ifn = lidx[2 * B_ + b];
    nll_buf[b] = (lseC - (float)row[OFFC + ic])
               + (lseM - (float)row[OFFM + im])
               + (lseF - (float)row[OFFF + ifn]);
    float4 pt = ptrig[NC_ + NM_ + ri[0]];
    float4 lt = ltrig[b];
    float cdla = lt.y * pt.y + lt.x * pt.x;
    float cdlo = lt.w * pt.w + lt.z * pt.z;
    float a = 0.5f * (1.f - cdla) + (lt.y * pt.y) * 0.5f * (1.f - cdlo);
    a = fminf(fmaxf(a, 0.f), 1.f);
    float d = 2.f * 6371.f * asinf(sqrtf(a));
    const float thr[5] = {1.f, 25.f, 200.f, 750.f, 2500.f};
#pragma unroll
    for (int j = 0; j < 5; ++j)
      if (d <= thr[j]) atomicAdd(accum + 1 + j, 1.f);
  }
}

__global__ void finish_kernel(const float* __restrict__ accum,
                              const float* __restrict__ nll, float* __restrict__ out) {
  __shared__ float sh[256];
  int tid = threadIdx.x;
  float s = 0.f;
  for (int i = tid; i < B_; i += 256) s += nll[i];
  sh[tid] = s;
  __syncthreads();
  for (int o = 128; o; o >>= 1) { if (tid < o) sh[tid] += sh[tid + o]; __syncthreads(); }
  if (tid == 0) out[0] = sh[0] * (1.f / 4096.f);
  if (tid >= 1 && tid < 6) out[tid] = accum[tid] * (1.f / 4096.f);
}

extern "C" void kernel_launch(void* const* d_in, const int* in_sizes, int n_in,
                              void* d_out, int out_size, void* d_ws, size_t ws_size,
                              hipStream_t stream) {
  (void)in_sizes; (void)n_in; (void)out_size; (void)ws_size;
  const float* features = (const float*)d_in[0];
  const float* labels   = (const float*)d_in[1];
  const float* cpart    = (const float*)d_in[2];
  const float* mpart    = (const float*)d_in[3];
  const float* fpart    = (const float*)d_in[4];
  const int*   mpar     = (const int*)d_in[5];
  const int*   fpar     = (const int*)d_in[6];
  const float* cw       = (const float*)d_in[7];
  const float* cb       = (const float*)d_in[8];
  const float* mw       = (const float*)d_in[9];
  const float* mb       = (const float*)d_in[10];
  const float* fw       = (const float*)d_in[11];
  const float* fb       = (const float*)d_in[12];
  float* out = (float*)d_out;

  char* ws = (char*)d_ws;
  size_t off = 0;
  auto alloc = [&](size_t bytes) {
    char* p = ws + off;
    off += (bytes + 255) & ~(size_t)255;
    return p;
  };
  // total ~237.6 MB (proven-passing footprint)
  _Float16* feat16 = (_Float16*)alloc((size_t)B_ * D_ * 2);        // 14.7 MB
  _Float16* wTbuf  = (_Float16*)alloc((size_t)WROWS * D_ * 2);     // 29.4 MB (32 col-tiles)
  _Float16* logits = (_Float16*)alloc((size_t)B_ * NTOT * 2);      // 193.0 MB
  float*    bias   = (float*)alloc((size_t)NTOT * 4);
  float4*   ptrig  = (float4*)alloc((size_t)(NC_ + NM_ + NF_) * 16);
  float4*   ltrig  = (float4*)alloc((size_t)B_ * 16);
  int*      lidx   = (int*)alloc((size_t)3 * B_ * 4);
  float*    nll    = (float*)alloc((size_t)B_ * 4);
  float*    accum  = (float*)alloc(64 * 4);

  prep_kernel<<<dim3(NTOT / 256), dim3(256), 0, stream>>>(labels, cpart, mpart, fpart,
                                                          cb, mb, fb, bias, ptrig, ltrig, accum);
  cvt_feat<<<dim3(B_ * D_ / 4 / 256), dim3(256), 0, stream>>>((const float4*)features,
                                                              (half4v*)feat16);
  argmin_kernel<<<dim3(B_), dim3(256), 0, stream>>>(ptrig, ltrig, lidx);

  // ---- 3 GEMM launches of 512/512/448 blocks; wTbuf holds 32 col-tiles each ----
  // L0: global col tiles 0..31 = coarse (12 tiles) + middle cols 0..5119 (20 tiles)
  transpose_w<<<dim3(3072 / 32, D_ / 32), dim3(32, 8), 0, stream>>>(cw, wTbuf, NC_, 0, NC_);
  transpose_w<<<dim3(5120 / 32, D_ / 32), dim3(32, 8), 0, stream>>>(mw, wTbuf + (size_t)3072 * D_, NM_, 0, 5120);
  gemm_f16<<<dim3(512), dim3(512), 0, stream>>>(feat16, wTbuf, bias, logits, 0);

  // L1: global col tiles 32..63 = middle cols 5120..7167 (8 tiles, pad) + fine 0..6143 (24 tiles)
  transpose_w<<<dim3(2048 / 32, D_ / 32), dim3(32, 8), 0, stream>>>(mw, wTbuf, NM_, 5120, NM_ - 5120);
  transpose_w<<<dim3(6144 / 32, D_ / 32), dim3(32, 8), 0, stream>>>(fw, wTbuf + (size_t)2048 * D_, NF_, 0, 6144);
  gemm_f16<<<dim3(512), dim3(512), 0, stream>>>(feat16, wTbuf, bias, logits, 8192);

  // L2: global col tiles 64..91 = fine cols 6144..13311 (28 tiles, pad)
  transpose_w<<<dim3(7168 / 32, D_ / 32), dim3(32, 8), 0, stream>>>(fw, wTbuf, NF_, 6144, NF_ - 6144);
  gemm_f16<<<dim3(448), dim3(512), 0, stream>>>(feat16, wTbuf, bias, logits, 16384);

  final_kernel<<<dim3(B_), dim3(256), 0, stream>>>(logits, mpar, fpar, ptrig, ltrig,
                                                   lidx, nll, accum);
  finish_kernel<<<dim3(1), dim3(256), 0, stream>>>(accum, nll, out);
}

// Round 7
// 750.973 us; speedup vs baseline: 1.0199x; 1.0199x over previous
//
#include <hip/hip_runtime.h>
#include <hip/hip_fp16.h>
#include <math.h>

#define B_   4096
#define D_   1792
#define NC_  3000
#define NM_  7000
#define NF_  13000
#define NCP  3072                /* 12 x 256 */
#define NMP  7168                /* 28 x 256 */
#define NFP  13312               /* 52 x 256 */
#define NTOT (NCP + NMP + NFP)   /* 23552 = 92 x 256 */
#define OFFC 0
#define OFFM NCP                 /* 3072 */
#define OFFF (NCP + NMP)         /* 10240 */
#define WROWS 8192               /* wTbuf rows: 32 col-tiles per GEMM launch */
#define DEG2RAD 0.017453292519943295f

typedef _Float16 half8  __attribute__((ext_vector_type(8)));
typedef _Float16 half4v __attribute__((ext_vector_type(4)));
typedef float    f32x4  __attribute__((ext_vector_type(4)));

__device__ __forceinline__ void async16(const void* g, void* l) {
  __builtin_amdgcn_global_load_lds(
      (const __attribute__((address_space(1))) void*)g,
      (__attribute__((address_space(3))) void*)l, 16, 0, 0);
}

// ---------------- prep: bias concat, trig tables, accumulator zero ----------------
__global__ void prep_kernel(const float* __restrict__ labels,
                            const float* __restrict__ cp, const float* __restrict__ mp,
                            const float* __restrict__ fp,
                            const float* __restrict__ cb, const float* __restrict__ mb,
                            const float* __restrict__ fb,
                            float* __restrict__ bias, float4* __restrict__ ptrig,
                            float4* __restrict__ ltrig, float* __restrict__ accum) {
  int i = blockIdx.x * 256 + threadIdx.x;
  if (i < NTOT) {
    float v = 0.f;
    if (i < OFFM)      { if (i < NC_) v = cb[i]; }
    else if (i < OFFF) { int j = i - OFFM; if (j < NM_) v = mb[j]; }
    else               { int j = i - OFFF; if (j < NF_) v = fb[j]; }
    bias[i] = v;
  }
  if (i < NC_ + NM_ + NF_) {
    const float* src; int j = i;
    if (i < NC_)            { src = cp; }
    else if (i < NC_ + NM_) { src = mp; j = i - NC_; }
    else                    { src = fp; j = i - NC_ - NM_; }
    float la = src[2 * j] * DEG2RAD, lo = src[2 * j + 1] * DEG2RAD;
    float sla, cla, slo, clo;
    sincosf(la, &sla, &cla); sincosf(lo, &slo, &clo);
    ptrig[i] = make_float4(sla, cla, slo, clo);
  }
  if (i < B_) {
    float la = labels[2 * i] * DEG2RAD, lo = labels[2 * i + 1] * DEG2RAD;
    float sla, cla, slo, clo;
    sincosf(la, &sla, &cla); sincosf(lo, &slo, &clo);
    ltrig[i] = make_float4(sla, cla, slo, clo);
  }
  if (i < 64) accum[i] = 0.f;
}

// ---------------- features fp32 -> fp16 ----------------
__global__ void cvt_feat(const float4* __restrict__ in, half4v* __restrict__ out) {
  int i = blockIdx.x * 256 + threadIdx.x;  // exactly B_*D_/4 threads
  float4 v = in[i];
  half4v h;
  h[0] = (_Float16)v.x; h[1] = (_Float16)v.y; h[2] = (_Float16)v.z; h[3] = (_Float16)v.w;
  out[i] = h;
}

// ---- weight chunk [K][Nfull] fp32 -> [rows][K] fp16 (transpose, pad rows -> 0) ----
__global__ void transpose_w(const float* __restrict__ w, _Float16* __restrict__ wt,
                            int Nfull, int c0, int ntrue_chunk) {
  __shared__ float tile[32][33];
  int n0 = blockIdx.x * 32, k0 = blockIdx.y * 32;
  int tx = threadIdx.x, ty = threadIdx.y;  // 32 x 8
#pragma unroll
  for (int i = 0; i < 4; ++i) {
    int kk = ty + i * 8;
    int n = n0 + tx;
    float v = (n < ntrue_chunk) ? w[(size_t)(k0 + kk) * Nfull + c0 + n] : 0.f;
    tile[kk][tx] = v;
  }
  __syncthreads();
#pragma unroll
  for (int i = 0; i < 4; ++i) {
    int nn = ty + i * 8;
    wt[(size_t)(n0 + nn) * D_ + k0 + tx] = (_Float16)tile[tx][nn];
  }
}

// ==== fp16 MFMA GEMM: 256x256 tile, 8 waves, 56 K-phases of 32, reg-pipelined ====
// (R5 structure; SGB experiment removed — measured null.)
// LDS (128 KiB, halfs): A regions r=0..3 at r*8192 (each [256r][4slot][8], K=32);
// B regions at 32768 + r*8192. Swizzle: slot s holds kb = s ^ ((row>>1)&3).
// Phase P: MFMAs consume frags loaded during P-1; af[tm] reloaded from region
// (P+1)%4 after its last use; bf after the cluster. stage(P) -> data(P+4).
// Boundary: s_waitcnt vmcnt(8) + lgkmcnt(0) + sched_barrier + s_barrier.
__global__ __launch_bounds__(512, 2) void gemm_f16(const _Float16* __restrict__ A,
                                                   const _Float16* __restrict__ Bt,
                                                   const float* __restrict__ bias,
                                                   _Float16* __restrict__ C, int coff) {
  __shared__ _Float16 lds[65536];   // 128 KiB
  const int tid = threadIdx.x;
  const int lane = tid & 63, w = tid >> 6;      // 8 waves
  const int wm = w & 1, wn = w >> 1;            // 2 (M) x 4 (N)
  const int q = lane >> 4, l15 = lane & 15;
  // bijective XCD swizzle (gridDim.x is always a multiple of 8)
  const int q8 = gridDim.x >> 3;
  const int bxr = blockIdx.x;
  const int bx = (bxr & 7) * q8 + (bxr >> 3);
  const int mt = bx & 15, nt = bx >> 4;         // grid = 16 x tiles
  const int m0 = mt * 256;
  const int nl0 = nt * 256;                     // wTbuf-local col base
  const int gn0 = coff + nl0;                   // global col base (bias / C)

  f32x4 acc[8][4];
#pragma unroll
  for (int a = 0; a < 8; ++a)
#pragma unroll
    for (int b2 = 0; b2 < 4; ++b2) acc[a][b2] = (f32x4){0.f, 0.f, 0.f, 0.f};

  const int amB = (wm * 128 + l15) * 32;
  const int bnB = (wn * 64 + l15) * 32;
  const int xsl = ((q ^ ((l15 >> 1) & 3)) << 3);
  const int kbl = (lane & 3) ^ ((lane >> 3) & 3);
  const int rr = lane >> 2;

  auto stageP = [&](int r, int P) {
    const int kk = P * 32 + kbl * 8;
#pragma unroll
    for (int j = 0; j < 2; ++j) {
      int seg = w * 2 + j;
      async16(A  + (size_t)(m0  + seg * 16 + rr) * D_ + kk,
              (void*)(lds + r * 8192 + seg * 512));
      async16(Bt + (size_t)(nl0 + seg * 16 + rr) * D_ + kk,
              (void*)(lds + 32768 + r * 8192 + seg * 512));
    }
  };

  half8 af[8], bf[4];

#define PHASE(RS, RN, WAITSTR, DOSTAGE, PST) { \
    if (DOSTAGE) stageP(RS, PST); \
    __builtin_amdgcn_s_setprio(1); \
    _Pragma("unroll") for (int tm = 0; tm < 8; ++tm) { \
      _Pragma("unroll") for (int tn = 0; tn < 4; ++tn) \
        acc[tm][tn] = __builtin_amdgcn_mfma_f32_16x16x32_f16(af[tm], bf[tn], acc[tm][tn], 0, 0, 0); \
      af[tm] = *(const half8*)(lds + (RN) * 8192 + amB + tm * 512 + xsl); \
    } \
    __builtin_amdgcn_s_setprio(0); \
    _Pragma("unroll") for (int tn = 0; tn < 4; ++tn) \
      bf[tn] = *(const half8*)(lds + 32768 + (RN) * 8192 + bnB + tn * 512 + xsl); \
    asm volatile(WAITSTR ::: "memory"); \
    __builtin_amdgcn_sched_barrier(0); \
    __builtin_amdgcn_s_barrier(); }

  // prologue: stage data(0..3); data(0),(1) complete; prefetch frags(data 0)
  stageP(0, 0); stageP(1, 1); stageP(2, 2); stageP(3, 3);
  asm volatile("s_waitcnt vmcnt(8)" ::: "memory");
  __builtin_amdgcn_sched_barrier(0);
  __builtin_amdgcn_s_barrier();
#pragma unroll
  for (int tm = 0; tm < 8; ++tm)
    af[tm] = *(const half8*)(lds + amB + tm * 512 + xsl);
#pragma unroll
  for (int tn = 0; tn < 4; ++tn)
    bf[tn] = *(const half8*)(lds + 32768 + bnB + tn * 512 + xsl);
  asm volatile("s_waitcnt lgkmcnt(0)" ::: "memory");
  __builtin_amdgcn_sched_barrier(0);
  __builtin_amdgcn_s_barrier();

  // main: phases 0..51 (13 iters x 4), stage P+4, vmcnt(8) boundaries
#pragma unroll 1
  for (int i = 0; i < 13; ++i) {
    const int P0 = 4 * i;
    PHASE(0, 1, "s_waitcnt vmcnt(8) lgkmcnt(0)", true, P0 + 4);
    PHASE(1, 2, "s_waitcnt vmcnt(8) lgkmcnt(0)", true, P0 + 5);
    PHASE(2, 3, "s_waitcnt vmcnt(8) lgkmcnt(0)", true, P0 + 6);
    PHASE(3, 0, "s_waitcnt vmcnt(8) lgkmcnt(0)", true, P0 + 7);
  }
  // epilogue: phases 52..55, no staging
  PHASE(0, 1, "s_waitcnt vmcnt(4) lgkmcnt(0)", false, 0);
  PHASE(0, 2, "s_waitcnt vmcnt(0) lgkmcnt(0)", false, 0);
  // phase 54: reload region 3 (data 55)
  {
    __builtin_amdgcn_s_setprio(1);
#pragma unroll
    for (int tm = 0; tm < 8; ++tm) {
#pragma unroll
      for (int tn = 0; tn < 4; ++tn)
        acc[tm][tn] = __builtin_amdgcn_mfma_f32_16x16x32_f16(af[tm], bf[tn], acc[tm][tn], 0, 0, 0);
      af[tm] = *(const half8*)(lds + 3 * 8192 + amB + tm * 512 + xsl);
    }
    __builtin_amdgcn_s_setprio(0);
#pragma unroll
    for (int tn = 0; tn < 4; ++tn)
      bf[tn] = *(const half8*)(lds + 32768 + 3 * 8192 + bnB + tn * 512 + xsl);
  }
  // phase 55: MFMA only
  {
    __builtin_amdgcn_s_setprio(1);
#pragma unroll
    for (int tm = 0; tm < 8; ++tm)
#pragma unroll
      for (int tn = 0; tn < 4; ++tn)
        acc[tm][tn] = __builtin_amdgcn_mfma_f32_16x16x32_f16(af[tm], bf[tn], acc[tm][tn], 0, 0, 0);
    __builtin_amdgcn_s_setprio(0);
  }
#undef PHASE

  // epilogue: bias add + fp16 store
  float bn[4];
#pragma unroll
  for (int tn = 0; tn < 4; ++tn) bn[tn] = bias[gn0 + wn * 64 + tn * 16 + l15];
#pragma unroll
  for (int tm = 0; tm < 8; ++tm) {
    int gm = m0 + wm * 128 + tm * 16 + q * 4;
#pragma unroll
    for (int tn = 0; tn < 4; ++tn) {
      int gn = gn0 + wn * 64 + tn * 16 + l15;
      _Float16* dst = C + (size_t)gm * NTOT + gn;
#pragma unroll
      for (int r = 0; r < 4; ++r) dst[(size_t)r * NTOT] = (_Float16)(acc[tm][tn][r] + bn[tn]);
    }
  }
}

// ------------- wave-level block reductions (512 threads, 8 waves) -------------
__device__ __forceinline__ void lse_comb(float& m, float& s, float m2, float s2) {
  float mn = fmaxf(m, m2);
  s = s * __expf(m - mn) + s2 * __expf(m2 - mn);
  m = mn;
}

__device__ __forceinline__ float block_lse(float m, float s, float* sm, float* ss, int tid) {
#pragma unroll
  for (int o = 32; o; o >>= 1)
    lse_comb(m, s, __shfl_xor(m, o), __shfl_xor(s, o));
  if ((tid & 63) == 0) { sm[tid >> 6] = m; ss[tid >> 6] = s; }
  __syncthreads();
  if (tid < 64) {
    m = sm[tid & 7]; s = ss[tid & 7];
#pragma unroll
    for (int o = 4; o; o >>= 1)
      lse_comb(m, s, __shfl_xor(m, o), __shfl_xor(s, o));
    if (tid == 0) sm[0] = m + logf(s);
  }
  __syncthreads();
  float r = sm[0];
  __syncthreads();   // protect sm/ss reuse by caller
  return r;
}

__device__ __forceinline__ int block_imin(float v, int idx, float* sv, int* si, int tid) {
#pragma unroll
  for (int o = 32; o; o >>= 1) {
    float v2 = __shfl_xor(v, o); int i2 = __shfl_xor(idx, o);
    if (v2 < v || (v2 == v && i2 < idx)) { v = v2; idx = i2; }
  }
  if ((tid & 63) == 0) { sv[tid >> 6] = v; si[tid >> 6] = idx; }
  __syncthreads();
  if (tid < 64) {
    v = sv[tid & 7]; idx = si[tid & 7];
#pragma unroll
    for (int o = 4; o; o >>= 1) {
      float v2 = __shfl_xor(v, o); int i2 = __shfl_xor(idx, o);
      if (v2 < v || (v2 == v && i2 < idx)) { v = v2; idx = i2; }
    }
    if (tid == 0) si[0] = idx;
  }
  __syncthreads();
  int r = si[0];
  __syncthreads();
  return r;
}

__device__ __forceinline__ int block_imax(float v, int idx, float* sv, int* si, int tid) {
#pragma unroll
  for (int o = 32; o; o >>= 1) {
    float v2 = __shfl_xor(v, o); int i2 = __shfl_xor(idx, o);
    if (v2 > v || (v2 == v && i2 < idx)) { v = v2; idx = i2; }
  }
  if ((tid & 63) == 0) { sv[tid >> 6] = v; si[tid >> 6] = idx; }
  __syncthreads();
  if (tid < 64) {
    v = sv[tid & 7]; idx = si[tid & 7];
#pragma unroll
    for (int o = 4; o; o >>= 1) {
      float v2 = __shfl_xor(v, o); int i2 = __shfl_xor(idx, o);
      if (v2 > v || (v2 == v && i2 < idx)) { v = v2; idx = i2; }
    }
    if (tid == 0) si[0] = idx;
  }
  __syncthreads();
  int r = si[0];
  __syncthreads();
  return r;
}

// -- fused: label argmin x3 + per-row LSE x3 + NLL + hierarchical argmax + acc --
// One 512-thread block per row.
__global__ __launch_bounds__(512) void final_kernel(const _Float16* __restrict__ logits,
                                                    const int* __restrict__ mpar,
                                                    const int* __restrict__ fpar,
                                                    const float4* __restrict__ ptrig,
                                                    const float4* __restrict__ ltrig,
                                                    float* __restrict__ nll_buf,
                                                    float* __restrict__ accum) {
  __shared__ float co[NC_];    // 12000 B
  __shared__ float par[NM_];   // 28000 B
  __shared__ float sv[8], sw[8];
  __shared__ int   si[8];
  int b = blockIdx.x, tid = threadIdx.x;
  const _Float16* row = logits + (size_t)b * NTOT;
  float4 lt = ltrig[b];

  // ---- haversine argmin per head (monotone: compare 'a' only) ----
  int lab[3];
  const int hbase[3] = {0, NC_, NC_ + NM_};
  const int hcnt[3]  = {NC_, NM_, NF_};
#pragma unroll
  for (int h = 0; h < 3; ++h) {
    float best = 1e30f; int bi = 0;
    for (int i = tid; i < hcnt[h]; i += 512) {
      float4 pt = ptrig[hbase[h] + i];
      float cdla = lt.y * pt.y + lt.x * pt.x;
      float cdlo = lt.w * pt.w + lt.z * pt.z;
      float a = 0.5f * (1.f - cdla) + (lt.y * pt.y) * 0.5f * (1.f - cdlo);
      if (a < best) { best = a; bi = i; }
    }
    lab[h] = block_imin(best, bi, sv, si, tid);
  }

  // ---- coarse: online LSE + stash fp32 copy to LDS ----
  float m = -1e30f, s = 0.f;
  {
    const half8* rc = (const half8*)(row + OFFC);
    for (int i = tid; i < NC_ / 8; i += 512) {
      half8 v = rc[i];
      float x[8];
#pragma unroll
      for (int j = 0; j < 8; ++j) x[j] = (float)v[j];
      float vm = fmaxf(fmaxf(fmaxf(x[0], x[1]), fmaxf(x[2], x[3])),
                       fmaxf(fmaxf(x[4], x[5]), fmaxf(x[6], x[7])));
      float mn = fmaxf(m, vm);
      s *= __expf(m - mn); m = mn;
#pragma unroll
      for (int j = 0; j < 8; ++j) s += __expf(x[j] - m);
      f32x4 lo = {x[0], x[1], x[2], x[3]}, hi = {x[4], x[5], x[6], x[7]};
      *(f32x4*)(co + i * 8)     = lo;
      *(f32x4*)(co + i * 8 + 4) = hi;
    }
  }
  float lseC = block_lse(m, s, sv, sw, tid);   // barriers fence co[] for readers

  // ---- middle: online LSE over raw logits; par = logit + co[mpar] ----
  m = -1e30f; s = 0.f;
  {
    const half8* rm = (const half8*)(row + OFFM);
    const int4* mp4 = (const int4*)mpar;
    for (int i = tid; i < NM_ / 8; i += 512) {
      half8 v = rm[i];
      int4 p0 = mp4[2 * i], p1 = mp4[2 * i + 1];
      float x[8];
#pragma unroll
      for (int j = 0; j < 8; ++j) x[j] = (float)v[j];
      float vm = fmaxf(fmaxf(fmaxf(x[0], x[1]), fmaxf(x[2], x[3])),
                       fmaxf(fmaxf(x[4], x[5]), fmaxf(x[6], x[7])));
      float mn = fmaxf(m, vm);
      s *= __expf(m - mn); m = mn;
#pragma unroll
      for (int j = 0; j < 8; ++j) s += __expf(x[j] - m);
      int pj[8] = {p0.x, p0.y, p0.z, p0.w, p1.x, p1.y, p1.z, p1.w};
      f32x4 lo = {x[0] + co[pj[0]], x[1] + co[pj[1]], x[2] + co[pj[2]], x[3] + co[pj[3]]};
      f32x4 hi = {x[4] + co[pj[4]], x[5] + co[pj[5]], x[6] + co[pj[6]], x[7] + co[pj[7]]};
      *(f32x4*)(par + i * 8)     = lo;
      *(f32x4*)(par + i * 8 + 4) = hi;
    }
  }
  float lseM = block_lse(m, s, sv, sw, tid);   // barriers fence par[] for readers

  // ---- fine: online LSE over raw logits; argmax of logit + par[fpar] ----
  m = -1e30f; s = 0.f;
  float best = -1e30f; int bi = 0;
  {
    const half8* rf = (const half8*)(row + OFFF);
    const int4* fp4 = (const int4*)fpar;
    for (int i = tid; i < NF_ / 8; i += 512) {
      half8 v = rf[i];
      int4 p0 = fp4[2 * i], p1 = fp4[2 * i + 1];
      float x[8];
#pragma unroll
      for (int j = 0; j < 8; ++j) x[j] = (float)v[j];
      float vm = fmaxf(fmaxf(fmaxf(x[0], x[1]), fmaxf(x[2], x[3])),
                       fmaxf(fmaxf(x[4], x[5]), fmaxf(x[6], x[7])));
      float mn = fmaxf(m, vm);
      s *= __expf(m - mn); m = mn;
#pragma unroll
      for (int j = 0; j < 8; ++j) s += __expf(x[j] - m);
      int pj[8] = {p0.x, p0.y, p0.z, p0.w, p1.x, p1.y, p1.z, p1.w};
#pragma unroll
      for (int j = 0; j < 8; ++j) {
        float vv = x[j] + par[pj[j]];
        if (vv > best) { best = vv; bi = i * 8 + j; }
      }
    }
  }
  float lseF = block_lse(m, s, sv, sw, tid);
  int fbest = block_imax(best, bi, sv, si, tid);

  if (tid == 0) {
    nll_buf[b] = (lseC - (float)row[OFFC + lab[0]])
               + (lseM - (float)row[OFFM + lab[1]])
               + (lseF - (float)row[OFFF + lab[2]]);
    float4 pt = ptrig[NC_ + NM_ + fbest];
    float cdla = lt.y * pt.y + lt.x * pt.x;
    float cdlo = lt.w * pt.w + lt.z * pt.z;
    float a = 0.5f * (1.f - cdla) + (lt.y * pt.y) * 0.5f * (1.f - cdlo);
    a = fminf(fmaxf(a, 0.f), 1.f);
    float d = 2.f * 6371.f * asinf(sqrtf(a));
    const float thr[5] = {1.f, 25.f, 200.f, 750.f, 2500.f};
#pragma unroll
    for (int j = 0; j < 5; ++j)
      if (d <= thr[j]) atomicAdd(accum + 1 + j, 1.f);
  }
}

__global__ void finish_kernel(const float* __restrict__ accum,
                              const float* __restrict__ nll, float* __restrict__ out) {
  __shared__ float sh[256];
  int tid = threadIdx.x;
  float s = 0.f;
  for (int i = tid; i < B_; i += 256) s += nll[i];
  sh[tid] = s;
  __syncthreads();
  for (int o = 128; o; o >>= 1) { if (tid < o) sh[tid] += sh[tid + o]; __syncthreads(); }
  if (tid == 0) out[0] = sh[0] * (1.f / 4096.f);
  if (tid >= 1 && tid < 6) out[tid] = accum[tid] * (1.f / 4096.f);
}

extern "C" void kernel_launch(void* const* d_in, const int* in_sizes, int n_in,
                              void* d_out, int out_size, void* d_ws, size_t ws_size,
                              hipStream_t stream) {
  (void)in_sizes; (void)n_in; (void)out_size; (void)ws_size;
  const float* features = (const float*)d_in[0];
  const float* labels   = (const float*)d_in[1];
  const float* cpart    = (const float*)d_in[2];
  const float* mpart    = (const float*)d_in[3];
  const float* fpart    = (const float*)d_in[4];
  const int*   mpar     = (const int*)d_in[5];
  const int*   fpar     = (const int*)d_in[6];
  const float* cw       = (const float*)d_in[7];
  const float* cb       = (const float*)d_in[8];
  const float* mw       = (const float*)d_in[9];
  const float* mb       = (const float*)d_in[10];
  const float* fw       = (const float*)d_in[11];
  const float* fb       = (const float*)d_in[12];
  float* out = (float*)d_out;

  char* ws = (char*)d_ws;
  size_t off = 0;
  auto alloc = [&](size_t bytes) {
    char* p = ws + off;
    off += (bytes + 255) & ~(size_t)255;
    return p;
  };
  // total ~237.5 MB (proven-passing footprint)
  _Float16* feat16 = (_Float16*)alloc((size_t)B_ * D_ * 2);        // 14.7 MB
  _Float16* wTbuf  = (_Float16*)alloc((size_t)WROWS * D_ * 2);     // 29.4 MB (32 col-tiles)
  _Float16* logits = (_Float16*)alloc((size_t)B_ * NTOT * 2);      // 193.0 MB
  float*    bias   = (float*)alloc((size_t)NTOT * 4);
  float4*   ptrig  = (float4*)alloc((size_t)(NC_ + NM_ + NF_) * 16);
  float4*   ltrig  = (float4*)alloc((size_t)B_ * 16);
  float*    nll    = (float*)alloc((size_t)B_ * 4);
  float*    accum  = (float*)alloc(64 * 4);

  prep_kernel<<<dim3(NTOT / 256), dim3(256), 0, stream>>>(labels, cpart, mpart, fpart,
                                                          cb, mb, fb, bias, ptrig, ltrig, accum);
  cvt_feat<<<dim3(B_ * D_ / 4 / 256), dim3(256), 0, stream>>>((const float4*)features,
                                                              (half4v*)feat16);

  // ---- 3 GEMM launches of 512/512/448 blocks; wTbuf holds 32 col-tiles each ----
  // L0: global col tiles 0..31 = coarse (12 tiles) + middle cols 0..5119 (20 tiles)
  transpose_w<<<dim3(3072 / 32, D_ / 32), dim3(32, 8), 0, stream>>>(cw, wTbuf, NC_, 0, NC_);
  transpose_w<<<dim3(5120 / 32, D_ / 32), dim3(32, 8), 0, stream>>>(mw, wTbuf + (size_t)3072 * D_, NM_, 0, 5120);
  gemm_f16<<<dim3(512), dim3(512), 0, stream>>>(feat16, wTbuf, bias, logits, 0);

  // L1: global col tiles 32..63 = middle cols 5120..7167 (8 tiles, pad) + fine 0..6143 (24 tiles)
  transpose_w<<<dim3(2048 / 32, D_ / 32), dim3(32, 8), 0, stream>>>(mw, wTbuf, NM_, 5120, NM_ - 5120);
  transpose_w<<<dim3(6144 / 32, D_ / 32), dim3(32, 8), 0, stream>>>(fw, wTbuf + (size_t)2048 * D_, NF_, 0, 6144);
  gemm_f16<<<dim3(512), dim3(512), 0, stream>>>(feat16, wTbuf, bias, logits, 8192);

  // L2: global col tiles 64..91 = fine cols 6144..13311 (28 tiles, pad)
  transpose_w<<<dim3(7168 / 32, D_ / 32), dim3(32, 8), 0, stream>>>(fw, wTbuf, NF_, 6144, NF_ - 6144);
  gemm_f16<<<dim3(448), dim3(512), 0, stream>>>(feat16, wTbuf, bias, logits, 16384);

  final_kernel<<<dim3(B_), dim3(512), 0, stream>>>(logits, mpar, fpar, ptrig, ltrig,
                                                   nll, accum);
  finish_kernel<<<dim3(1), dim3(256), 0, stream>>>(accum, nll, out);
}

// Round 8
// 722.394 us; speedup vs baseline: 1.0602x; 1.0396x over previous
//
#include <hip/hip_runtime.h>
#include <hip/hip_fp16.h>
#include <math.h>

#define B_   4096
#define D_   1792
#define NC_  3000
#define NM_  7000
#define NF_  13000
#define NCP  3072                /* 12 x 256 */
#define NMP  7168                /* 28 x 256 */
#define NFP  13312               /* 52 x 256 */
#define NTOT (NCP + NMP + NFP)   /* 23552 = 92 x 256 */
#define OFFC 0
#define OFFM NCP                 /* 3072 */
#define OFFF (NCP + NMP)         /* 10240 */
#define WROWS 8192               /* wTbuf rows: 32 col-tiles per GEMM launch */
#define DEG2RAD 0.017453292519943295f

typedef _Float16 half8  __attribute__((ext_vector_type(8)));
typedef _Float16 half4v __attribute__((ext_vector_type(4)));
typedef float    f32x4  __attribute__((ext_vector_type(4)));

__device__ __forceinline__ void async16(const void* g, void* l) {
  __builtin_amdgcn_global_load_lds(
      (const __attribute__((address_space(1))) void*)g,
      (__attribute__((address_space(3))) void*)l, 16, 0, 0);
}

// ---- prep: bias concat, unit-vector tables (haversine == 3D dot), accum zero ----
// u = (sin lat, cos lat * cos lon, cos lat * sin lon); a = 0.5*(1 - u.v) exactly.
__global__ void prep_kernel(const float* __restrict__ labels,
                            const float* __restrict__ cp, const float* __restrict__ mp,
                            const float* __restrict__ fp,
                            const float* __restrict__ cb, const float* __restrict__ mb,
                            const float* __restrict__ fb,
                            float* __restrict__ bias, float4* __restrict__ ptrig,
                            float4* __restrict__ ltrig, float* __restrict__ accum) {
  int i = blockIdx.x * 256 + threadIdx.x;
  if (i < NTOT) {
    float v = 0.f;
    if (i < OFFM)      { if (i < NC_) v = cb[i]; }
    else if (i < OFFF) { int j = i - OFFM; if (j < NM_) v = mb[j]; }
    else               { int j = i - OFFF; if (j < NF_) v = fb[j]; }
    bias[i] = v;
  }
  if (i < NC_ + NM_ + NF_) {
    const float* src; int j = i;
    if (i < NC_)            { src = cp; }
    else if (i < NC_ + NM_) { src = mp; j = i - NC_; }
    else                    { src = fp; j = i - NC_ - NM_; }
    float la = src[2 * j] * DEG2RAD, lo = src[2 * j + 1] * DEG2RAD;
    float sla, cla, slo, clo;
    sincosf(la, &sla, &cla); sincosf(lo, &slo, &clo);
    ptrig[i] = make_float4(sla, cla * clo, cla * slo, 0.f);
  }
  if (i < B_) {
    float la = labels[2 * i] * DEG2RAD, lo = labels[2 * i + 1] * DEG2RAD;
    float sla, cla, slo, clo;
    sincosf(la, &sla, &cla); sincosf(lo, &slo, &clo);
    ltrig[i] = make_float4(sla, cla * clo, cla * slo, 0.f);
  }
  if (i < 64) accum[i] = 0.f;
}

// ---------------- features fp32 -> fp16 ----------------
__global__ void cvt_feat(const float4* __restrict__ in, half4v* __restrict__ out) {
  int i = blockIdx.x * 256 + threadIdx.x;  // exactly B_*D_/4 threads
  float4 v = in[i];
  half4v h;
  h[0] = (_Float16)v.x; h[1] = (_Float16)v.y; h[2] = (_Float16)v.z; h[3] = (_Float16)v.w;
  out[i] = h;
}

// ---- weight chunk [K][Nfull] fp32 -> [rows][K] fp16 (transpose, pad rows -> 0) ----
__global__ void transpose_w(const float* __restrict__ w, _Float16* __restrict__ wt,
                            int Nfull, int c0, int ntrue_chunk) {
  __shared__ float tile[32][33];
  int n0 = blockIdx.x * 32, k0 = blockIdx.y * 32;
  int tx = threadIdx.x, ty = threadIdx.y;  // 32 x 8
#pragma unroll
  for (int i = 0; i < 4; ++i) {
    int kk = ty + i * 8;
    int n = n0 + tx;
    float v = (n < ntrue_chunk) ? w[(size_t)(k0 + kk) * Nfull + c0 + n] : 0.f;
    tile[kk][tx] = v;
  }
  __syncthreads();
#pragma unroll
  for (int i = 0; i < 4; ++i) {
    int nn = ty + i * 8;
    wt[(size_t)(n0 + nn) * D_ + k0 + tx] = (_Float16)tile[tx][nn];
  }
}

// ==== fp16 MFMA GEMM: 256x256 tile, 8 waves, 56 K-phases of 32, reg-pipelined ====
// (R5 structure — measured 49% MfmaUtil; two scheduling nulls => at this
// structure's ceiling, left untouched.)
__global__ __launch_bounds__(512, 2) void gemm_f16(const _Float16* __restrict__ A,
                                                   const _Float16* __restrict__ Bt,
                                                   const float* __restrict__ bias,
                                                   _Float16* __restrict__ C, int coff) {
  __shared__ _Float16 lds[65536];   // 128 KiB
  const int tid = threadIdx.x;
  const int lane = tid & 63, w = tid >> 6;      // 8 waves
  const int wm = w & 1, wn = w >> 1;            // 2 (M) x 4 (N)
  const int q = lane >> 4, l15 = lane & 15;
  // bijective XCD swizzle (gridDim.x is always a multiple of 8)
  const int q8 = gridDim.x >> 3;
  const int bxr = blockIdx.x;
  const int bx = (bxr & 7) * q8 + (bxr >> 3);
  const int mt = bx & 15, nt = bx >> 4;         // grid = 16 x tiles
  const int m0 = mt * 256;
  const int nl0 = nt * 256;                     // wTbuf-local col base
  const int gn0 = coff + nl0;                   // global col base (bias / C)

  f32x4 acc[8][4];
#pragma unroll
  for (int a = 0; a < 8; ++a)
#pragma unroll
    for (int b2 = 0; b2 < 4; ++b2) acc[a][b2] = (f32x4){0.f, 0.f, 0.f, 0.f};

  const int amB = (wm * 128 + l15) * 32;
  const int bnB = (wn * 64 + l15) * 32;
  const int xsl = ((q ^ ((l15 >> 1) & 3)) << 3);
  const int kbl = (lane & 3) ^ ((lane >> 3) & 3);
  const int rr = lane >> 2;

  auto stageP = [&](int r, int P) {
    const int kk = P * 32 + kbl * 8;
#pragma unroll
    for (int j = 0; j < 2; ++j) {
      int seg = w * 2 + j;
      async16(A  + (size_t)(m0  + seg * 16 + rr) * D_ + kk,
              (void*)(lds + r * 8192 + seg * 512));
      async16(Bt + (size_t)(nl0 + seg * 16 + rr) * D_ + kk,
              (void*)(lds + 32768 + r * 8192 + seg * 512));
    }
  };

  half8 af[8], bf[4];

#define PHASE(RS, RN, WAITSTR, DOSTAGE, PST) { \
    if (DOSTAGE) stageP(RS, PST); \
    __builtin_amdgcn_s_setprio(1); \
    _Pragma("unroll") for (int tm = 0; tm < 8; ++tm) { \
      _Pragma("unroll") for (int tn = 0; tn < 4; ++tn) \
        acc[tm][tn] = __builtin_amdgcn_mfma_f32_16x16x32_f16(af[tm], bf[tn], acc[tm][tn], 0, 0, 0); \
      af[tm] = *(const half8*)(lds + (RN) * 8192 + amB + tm * 512 + xsl); \
    } \
    __builtin_amdgcn_s_setprio(0); \
    _Pragma("unroll") for (int tn = 0; tn < 4; ++tn) \
      bf[tn] = *(const half8*)(lds + 32768 + (RN) * 8192 + bnB + tn * 512 + xsl); \
    asm volatile(WAITSTR ::: "memory"); \
    __builtin_amdgcn_sched_barrier(0); \
    __builtin_amdgcn_s_barrier(); }

  // prologue: stage data(0..3); data(0),(1) complete; prefetch frags(data 0)
  stageP(0, 0); stageP(1, 1); stageP(2, 2); stageP(3, 3);
  asm volatile("s_waitcnt vmcnt(8)" ::: "memory");
  __builtin_amdgcn_sched_barrier(0);
  __builtin_amdgcn_s_barrier();
#pragma unroll
  for (int tm = 0; tm < 8; ++tm)
    af[tm] = *(const half8*)(lds + amB + tm * 512 + xsl);
#pragma unroll
  for (int tn = 0; tn < 4; ++tn)
    bf[tn] = *(const half8*)(lds + 32768 + bnB + tn * 512 + xsl);
  asm volatile("s_waitcnt lgkmcnt(0)" ::: "memory");
  __builtin_amdgcn_sched_barrier(0);
  __builtin_amdgcn_s_barrier();

  // main: phases 0..51 (13 iters x 4), stage P+4, vmcnt(8) boundaries
#pragma unroll 1
  for (int i = 0; i < 13; ++i) {
    const int P0 = 4 * i;
    PHASE(0, 1, "s_waitcnt vmcnt(8) lgkmcnt(0)", true, P0 + 4);
    PHASE(1, 2, "s_waitcnt vmcnt(8) lgkmcnt(0)", true, P0 + 5);
    PHASE(2, 3, "s_waitcnt vmcnt(8) lgkmcnt(0)", true, P0 + 6);
    PHASE(3, 0, "s_waitcnt vmcnt(8) lgkmcnt(0)", true, P0 + 7);
  }
  // epilogue: phases 52..55, no staging
  PHASE(0, 1, "s_waitcnt vmcnt(4) lgkmcnt(0)", false, 0);
  PHASE(0, 2, "s_waitcnt vmcnt(0) lgkmcnt(0)", false, 0);
  // phase 54: reload region 3 (data 55)
  {
    __builtin_amdgcn_s_setprio(1);
#pragma unroll
    for (int tm = 0; tm < 8; ++tm) {
#pragma unroll
      for (int tn = 0; tn < 4; ++tn)
        acc[tm][tn] = __builtin_amdgcn_mfma_f32_16x16x32_f16(af[tm], bf[tn], acc[tm][tn], 0, 0, 0);
      af[tm] = *(const half8*)(lds + 3 * 8192 + amB + tm * 512 + xsl);
    }
    __builtin_amdgcn_s_setprio(0);
#pragma unroll
    for (int tn = 0; tn < 4; ++tn)
      bf[tn] = *(const half8*)(lds + 32768 + 3 * 8192 + bnB + tn * 512 + xsl);
  }
  // phase 55: MFMA only
  {
    __builtin_amdgcn_s_setprio(1);
#pragma unroll
    for (int tm = 0; tm < 8; ++tm)
#pragma unroll
      for (int tn = 0; tn < 4; ++tn)
        acc[tm][tn] = __builtin_amdgcn_mfma_f32_16x16x32_f16(af[tm], bf[tn], acc[tm][tn], 0, 0, 0);
    __builtin_amdgcn_s_setprio(0);
  }
#undef PHASE

  // epilogue: bias add + fp16 store
  float bn[4];
#pragma unroll
  for (int tn = 0; tn < 4; ++tn) bn[tn] = bias[gn0 + wn * 64 + tn * 16 + l15];
#pragma unroll
  for (int tm = 0; tm < 8; ++tm) {
    int gm = m0 + wm * 128 + tm * 16 + q * 4;
#pragma unroll
    for (int tn = 0; tn < 4; ++tn) {
      int gn = gn0 + wn * 64 + tn * 16 + l15;
      _Float16* dst = C + (size_t)gm * NTOT + gn;
#pragma unroll
      for (int r = 0; r < 4; ++r) dst[(size_t)r * NTOT] = (_Float16)(acc[tm][tn][r] + bn[tn]);
    }
  }
}

// ------------- wave-level block reductions (512 threads, 8 waves) -------------
__device__ __forceinline__ float block_sum(float s, float* sh, int tid) {
#pragma unroll
  for (int o = 32; o; o >>= 1) s += __shfl_xor(s, o);
  if ((tid & 63) == 0) sh[tid >> 6] = s;
  __syncthreads();
  if (tid < 64) {
    float v = sh[tid & 7];
#pragma unroll
    for (int o = 4; o; o >>= 1) v += __shfl_xor(v, o);
    if (tid == 0) sh[0] = v;
  }
  __syncthreads();
  float r = sh[0];
  __syncthreads();   // protect sh reuse by caller
  return r;
}

__device__ __forceinline__ int block_imax(float v, int idx, float* sv, int* si, int tid) {
#pragma unroll
  for (int o = 32; o; o >>= 1) {
    float v2 = __shfl_xor(v, o); int i2 = __shfl_xor(idx, o);
    if (v2 > v || (v2 == v && i2 < idx)) { v = v2; idx = i2; }
  }
  if ((tid & 63) == 0) { sv[tid >> 6] = v; si[tid >> 6] = idx; }
  __syncthreads();
  if (tid < 64) {
    v = sv[tid & 7]; idx = si[tid & 7];
#pragma unroll
    for (int o = 4; o; o >>= 1) {
      float v2 = __shfl_xor(v, o); int i2 = __shfl_xor(idx, o);
      if (v2 > v || (v2 == v && i2 < idx)) { v = v2; idx = i2; }
    }
    if (tid == 0) si[0] = idx;
  }
  __syncthreads();
  int r = si[0];
  __syncthreads();
  return r;
}

// -- fused: label argmin x3 + per-row LSE x3 + NLL + hierarchical argmax + acc --
// One 512-thread block per row. Argmin via 3D-dot argmax (exact identity);
// LSE without max-tracking (logits bounded ~|6| => no overflow; fp32-exact).
__global__ __launch_bounds__(512) void final_kernel(const _Float16* __restrict__ logits,
                                                    const int* __restrict__ mpar,
                                                    const int* __restrict__ fpar,
                                                    const float4* __restrict__ ptrig,
                                                    const float4* __restrict__ ltrig,
                                                    float* __restrict__ nll_buf,
                                                    float* __restrict__ accum) {
  __shared__ float co[NC_];    // 12000 B
  __shared__ float par[NM_];   // 28000 B
  __shared__ float sv[8];
  __shared__ int   si[8];
  int b = blockIdx.x, tid = threadIdx.x;
  const _Float16* row = logits + (size_t)b * NTOT;
  float4 lt = ltrig[b];

  // ---- nearest-partition label per head: argmax of u.v (== argmin haversine) ----
  int lab[3];
  const int hbase[3] = {0, NC_, NC_ + NM_};
  const int hcnt[3]  = {NC_, NM_, NF_};
#pragma unroll
  for (int h = 0; h < 3; ++h) {
    float best = -1e30f; int bi = 0;
    for (int i = tid; i < hcnt[h]; i += 512) {
      float4 pt = ptrig[hbase[h] + i];
      float f = lt.x * pt.x + lt.y * pt.y + lt.z * pt.z;
      if (f > best) { best = f; bi = i; }
    }
    lab[h] = block_imax(best, bi, sv, si, tid);
  }

  // ---- coarse: sum-exp + stash fp32 copy to LDS ----
  float s = 0.f;
  {
    const half8* rc = (const half8*)(row + OFFC);
    for (int i = tid; i < NC_ / 8; i += 512) {
      half8 v = rc[i];
      float x[8];
#pragma unroll
      for (int j = 0; j < 8; ++j) x[j] = (float)v[j];
#pragma unroll
      for (int j = 0; j < 8; ++j) s += __expf(x[j]);
      f32x4 lo = {x[0], x[1], x[2], x[3]}, hi = {x[4], x[5], x[6], x[7]};
      *(f32x4*)(co + i * 8)     = lo;
      *(f32x4*)(co + i * 8 + 4) = hi;
    }
  }
  float lseC = logf(block_sum(s, sv, tid));   // barriers fence co[] for readers

  // ---- middle: sum-exp; par = logit + co[mpar] ----
  s = 0.f;
  {
    const half8* rm = (const half8*)(row + OFFM);
    const int4* mp4 = (const int4*)mpar;
    for (int i = tid; i < NM_ / 8; i += 512) {
      half8 v = rm[i];
      int4 p0 = mp4[2 * i], p1 = mp4[2 * i + 1];
      float x[8];
#pragma unroll
      for (int j = 0; j < 8; ++j) x[j] = (float)v[j];
#pragma unroll
      for (int j = 0; j < 8; ++j) s += __expf(x[j]);
      int pj[8] = {p0.x, p0.y, p0.z, p0.w, p1.x, p1.y, p1.z, p1.w};
      f32x4 lo = {x[0] + co[pj[0]], x[1] + co[pj[1]], x[2] + co[pj[2]], x[3] + co[pj[3]]};
      f32x4 hi = {x[4] + co[pj[4]], x[5] + co[pj[5]], x[6] + co[pj[6]], x[7] + co[pj[7]]};
      *(f32x4*)(par + i * 8)     = lo;
      *(f32x4*)(par + i * 8 + 4) = hi;
    }
  }
  float lseM = logf(block_sum(s, sv, tid));   // barriers fence par[] for readers

  // ---- fine: sum-exp; argmax of logit + par[fpar] ----
  s = 0.f;
  float best = -1e30f; int bi = 0;
  {
    const half8* rf = (const half8*)(row + OFFF);
    const int4* fp4 = (const int4*)fpar;
    for (int i = tid; i < NF_ / 8; i += 512) {
      half8 v = rf[i];
      int4 p0 = fp4[2 * i], p1 = fp4[2 * i + 1];
      float x[8];
#pragma unroll
      for (int j = 0; j < 8; ++j) x[j] = (float)v[j];
#pragma unroll
      for (int j = 0; j < 8; ++j) s += __expf(x[j]);
      int pj[8] = {p0.x, p0.y, p0.z, p0.w, p1.x, p1.y, p1.z, p1.w};
#pragma unroll
      for (int j = 0; j < 8; ++j) {
        float vv = x[j] + par[pj[j]];
        if (vv > best) { best = vv; bi = i * 8 + j; }
      }
    }
  }
  float lseF = logf(block_sum(s, sv, tid));
  int fbest = block_imax(best, bi, sv, si, tid);

  if (tid == 0) {
    nll_buf[b] = (lseC - (float)row[OFFC + lab[0]])
               + (lseM - (float)row[OFFM + lab[1]])
               + (lseF - (float)row[OFFF + lab[2]]);
    float4 pt = ptrig[NC_ + NM_ + fbest];
    float dot = lt.x * pt.x + lt.y * pt.y + lt.z * pt.z;
    float a = fminf(fmaxf(0.5f - 0.5f * dot, 0.f), 1.f);
    float d = 2.f * 6371.f * asinf(sqrtf(a));
    const float thr[5] = {1.f, 25.f, 200.f, 750.f, 2500.f};
#pragma unroll
    for (int j = 0; j < 5; ++j)
      if (d <= thr[j]) atomicAdd(accum + 1 + j, 1.f);
  }
}

__global__ void finish_kernel(const float* __restrict__ accum,
                              const float* __restrict__ nll, float* __restrict__ out) {
  __shared__ float sh[256];
  int tid = threadIdx.x;
  float s = 0.f;
  for (int i = tid; i < B_; i += 256) s += nll[i];
  sh[tid] = s;
  __syncthreads();
  for (int o = 128; o; o >>= 1) { if (tid < o) sh[tid] += sh[tid + o]; __syncthreads(); }
  if (tid == 0) out[0] = sh[0] * (1.f / 4096.f);
  if (tid >= 1 && tid < 6) out[tid] = accum[tid] * (1.f / 4096.f);
}

extern "C" void kernel_launch(void* const* d_in, const int* in_sizes, int n_in,
                              void* d_out, int out_size, void* d_ws, size_t ws_size,
                              hipStream_t stream) {
  (void)in_sizes; (void)n_in; (void)out_size; (void)ws_size;
  const float* features = (const float*)d_in[0];
  const float* labels   = (const float*)d_in[1];
  const float* cpart    = (const float*)d_in[2];
  const float* mpart    = (const float*)d_in[3];
  const float* fpart    = (const float*)d_in[4];
  const int*   mpar     = (const int*)d_in[5];
  const int*   fpar     = (const int*)d_in[6];
  const float* cw       = (const float*)d_in[7];
  const float* cb       = (const float*)d_in[8];
  const float* mw       = (const float*)d_in[9];
  const float* mb       = (const float*)d_in[10];
  const float* fw       = (const float*)d_in[11];
  const float* fb       = (const float*)d_in[12];
  float* out = (float*)d_out;

  char* ws = (char*)d_ws;
  size_t off = 0;
  auto alloc = [&](size_t bytes) {
    char* p = ws + off;
    off += (bytes + 255) & ~(size_t)255;
    return p;
  };
  // total ~237.5 MB (proven-passing footprint)
  _Float16* feat16 = (_Float16*)alloc((size_t)B_ * D_ * 2);        // 14.7 MB
  _Float16* wTbuf  = (_Float16*)alloc((size_t)WROWS * D_ * 2);     // 29.4 MB (32 col-tiles)
  _Float16* logits = (_Float16*)alloc((size_t)B_ * NTOT * 2);      // 193.0 MB
  float*    bias   = (float*)alloc((size_t)NTOT * 4);
  float4*   ptrig  = (float4*)alloc((size_t)(NC_ + NM_ + NF_) * 16);
  float4*   ltrig  = (float4*)alloc((size_t)B_ * 16);
  float*    nll    = (float*)alloc((size_t)B_ * 4);
  float*    accum  = (float*)alloc(64 * 4);

  prep_kernel<<<dim3(NTOT / 256), dim3(256), 0, stream>>>(labels, cpart, mpart, fpart,
                                                          cb, mb, fb, bias, ptrig, ltrig, accum);
  cvt_feat<<<dim3(B_ * D_ / 4 / 256), dim3(256), 0, stream>>>((const float4*)features,
                                                              (half4v*)feat16);

  // ---- 3 GEMM launches of 512/512/448 blocks; wTbuf holds 32 col-tiles each ----
  // L0: global col tiles 0..31 = coarse (12 tiles) + middle cols 0..5119 (20 tiles)
  transpose_w<<<dim3(3072 / 32, D_ / 32), dim3(32, 8), 0, stream>>>(cw, wTbuf, NC_, 0, NC_);
  transpose_w<<<dim3(5120 / 32, D_ / 32), dim3(32, 8), 0, stream>>>(mw, wTbuf + (size_t)3072 * D_, NM_, 0, 5120);
  gemm_f16<<<dim3(512), dim3(512), 0, stream>>>(feat16, wTbuf, bias, logits, 0);

  // L1: global col tiles 32..63 = middle cols 5120..7167 (8 tiles, pad) + fine 0..6143 (24 tiles)
  transpose_w<<<dim3(2048 / 32, D_ / 32), dim3(32, 8), 0, stream>>>(mw, wTbuf, NM_, 5120, NM_ - 5120);
  transpose_w<<<dim3(6144 / 32, D_ / 32), dim3(32, 8), 0, stream>>>(fw, wTbuf + (size_t)2048 * D_, NF_, 0, 6144);
  gemm_f16<<<dim3(512), dim3(512), 0, stream>>>(feat16, wTbuf, bias, logits, 8192);

  // L2: global col tiles 64..91 = fine cols 6144..13311 (28 tiles, pad)
  transpose_w<<<dim3(7168 / 32, D_ / 32), dim3(32, 8), 0, stream>>>(fw, wTbuf, NF_, 6144, NF_ - 6144);
  gemm_f16<<<dim3(448), dim3(512), 0, stream>>>(feat16, wTbuf, bias, logits, 16384);

  final_kernel<<<dim3(B_), dim3(512), 0, stream>>>(logits, mpar, fpar, ptrig, ltrig,
                                                   nll, accum);
  finish_kernel<<<dim3(1), dim3(256), 0, stream>>>(accum, nll, out);
}